// Round 1
// 111.534 us; speedup vs baseline: 1.0042x; 1.0042x over previous
//
#include <hip/hip_runtime.h>
#include <math.h>

// Problem constants (from reference setup_inputs)
#define BATCH 64
#define V0 32768          // 32^3
#define V1 4096           // 16^3
#define V2 512            // 8^3
#define NTOT 37376
#define K 20              // NMS_TOPK
#define M_OUT 180         // 3 * TOPK
#define NT 1024           // fused kernel: threads per block (one block per image)
#define NTF 256           // fallback path: virtual block size (proven R2 structure)
#define NKEY 128          // candidate capacity (mean ~50 at TLOG=3.0, 11 sigma margin)
#define TLOG 3.0f         // logit filter; 20th-largest logit ~ 3.27 (z-quantile)

// R5 (this round): fused single-kernel design. Previous 2-kernel split
// (scan 2048 blocks -> ws -> final 64 blocks) paid one kernel boundary
// (full waitcnt+L2 drain), a 2nd graph node, and a ws write/read round
// trip. Profile showed the top dispatches are the harness's 256 MiB ws
// poisons (~41 us each @ 80% HBM peak) -- our kernels are small, so the
// remaining controllable cost is exactly that boundary + ws latency.
// One 1024-thread block per image reads its 146 KB cls slice with 10
// outstanding float4 loads/thread (L3-resident after iter 1), filters
// at TLOG into shared, then rank-select/decode/IoU/NMS/write in-block.
//
// NOTE (R4 post-mortem, kept): do NOT fuse via cross-block agent-scope
// acq_rel atomics -- each release implies a full L2 writeback on gfx950
// (per-XCD L2s non-coherent); that variant serialized to ~85 us.
// This fusion is intra-block only: no cross-block communication at all.

// Sort key: (fp32 sigmoid score bits << 32) | ~g.
// Descending u64 order == (score desc, global index asc) — matches the
// reference's lax.top_k + stable argsort tie semantics exactly.
__device__ __forceinline__ unsigned long long make_key_lo(float logit, unsigned int lo /* = ~g */) {
    float s = 1.0f / (1.0f + expf(-logit));
    return ((unsigned long long)__float_as_uint(s) << 32) | (unsigned long long)lo;
}

// Unrolled register-resident sorted-descending top-K insert (u64 keys).
#define INSERT(LV, GG) do {                                             \
    unsigned long long ck_ = make_key_lo((LV), ~(GG));                  \
    if (ck_ > keys[K-1]) {                                              \
        _Pragma("unroll")                                               \
        for (int j_ = 0; j_ < K; ++j_) {                                \
            if (ck_ > keys[j_]) {                                       \
                unsigned long long t_ = keys[j_]; keys[j_] = ck_; ck_ = t_; \
            }                                                           \
        }                                                               \
    }                                                                   \
} while (0)

// Threshold-filter 4 logits into the shared candidate buffer.
#define SCAN4(VV, GG) do {                                              \
    float a_[4] = {(VV).x, (VV).y, (VV).z, (VV).w};                     \
    _Pragma("unroll")                                                   \
    for (int c_ = 0; c_ < 4; ++c_) {                                    \
        if (a_[c_] > TLOG) {                                            \
            int slot_ = atomicAdd(&sCnt, 1);                            \
            if (slot_ < NKEY)                                           \
                lkeys[slot_] =                                          \
                    ((unsigned long long)__float_as_uint(a_[c_]) << 32) \
                    | (unsigned long long)(~((GG) + (unsigned int)c_)); \
        }                                                               \
    }                                                                   \
} while (0)

__global__ __launch_bounds__(NT) void fused_kernel(
    const float* __restrict__ cls0, const float* __restrict__ shp0, const float* __restrict__ off0,
    const float* __restrict__ cls1, const float* __restrict__ shp1, const float* __restrict__ off1,
    const float* __restrict__ cls2, const float* __restrict__ shp2, const float* __restrict__ off2,
    float* __restrict__ out)
{
    const int b   = blockIdx.x;
    const int tid = threadIdx.x;

    __shared__ unsigned long long sKeys[NTF * K];   // 40 KB (fallback merge space)
    __shared__ unsigned long long lkeys[NKEY];
    __shared__ unsigned long long sorted[K];
    __shared__ int sCnt;
    __shared__ float sBox[K][6];
    __shared__ float sScore[K];
    __shared__ int   sValid[K];
    __shared__ float sIou[K * K];
    __shared__ int   sRow[K];

    if (tid == 0) sCnt = 0;
    __syncthreads();

    // -------- Phase 1: threshold scan of this image's logits --------
    // V0/4 = 8192 = 8*NT, V1/4 = 1024 = NT, V2/4 = 128. Issue all loads
    // up front (10 outstanding per thread) so HBM/L3 latency is paid once.
    {
        const float4* c0 = (const float4*)(cls0 + (size_t)b * V0);
        const float4* c1 = (const float4*)(cls1 + (size_t)b * V1);
        const float4* c2 = (const float4*)(cls2 + (size_t)b * V2);
        float4 vv[10];
#pragma unroll
        for (int it = 0; it < 8; ++it) vv[it] = c0[tid + it * NT];
        vv[8] = c1[tid];
        if (tid < V2 / 4) vv[9] = c2[tid];

#pragma unroll
        for (int it = 0; it < 8; ++it) {
            unsigned int g = 4u * (unsigned int)(tid + it * NT);
            SCAN4(vv[it], g);
        }
        {
            unsigned int g = V0 + 4u * (unsigned int)tid;
            SCAN4(vv[8], g);
        }
        if (tid < V2 / 4) {
            unsigned int g = V0 + V1 + 4u * (unsigned int)tid;
            SCAN4(vv[9], g);
        }
    }
    __syncthreads();

    const int total = sCnt;
    const bool degen = (total < K) || (total > NKEY);   // block-uniform

    if (!degen) {
        // -------- fast path: exact rank-select top-20 among survivors --------
        // (>= K candidates all with logit > TLOG => global top-20 is among them)
        if (tid < NKEY) {
            unsigned long long key = 0ull;
            if (tid < total) {
                unsigned long long pk = lkeys[tid];
                float logit = __uint_as_float((unsigned int)(pk >> 32));
                key = make_key_lo(logit, (unsigned int)pk);
            }
            lkeys[tid] = key;
        }
        __syncthreads();
        if (tid < NKEY) {
            unsigned long long my = lkeys[tid];
            int rank = 0;
#pragma unroll 8
            for (int i = 0; i < NKEY; ++i) rank += (lkeys[i] > my) ? 1 : 0;
            if (my != 0ull && rank < K) sorted[rank] = my;  // keys distinct => ranks unique
        }
        __syncthreads();
    } else {
        // -------- exact fallback: full-image scan (R2-proven path) --------
        // First NTF threads do the per-thread top-K scan; all threads
        // participate in the (uniform-trip-count) barrier merge tree.
        unsigned long long keys[K];
#pragma unroll
        for (int j = 0; j < K; ++j) keys[j] = 0ull;
        if (tid < NTF) {
            const float4* c0 = (const float4*)(cls0 + (size_t)b * V0);
#pragma unroll 1
            for (int it = 0; it < V0 / (4 * NTF); ++it) {
                int i4 = tid + it * NTF;
                float4 v = c0[i4];
                unsigned int g = 4u * (unsigned int)i4;
                INSERT(v.x, g); INSERT(v.y, g + 1); INSERT(v.z, g + 2); INSERT(v.w, g + 3);
            }
            const float4* c1 = (const float4*)(cls1 + (size_t)b * V1);
#pragma unroll 1
            for (int it = 0; it < V1 / (4 * NTF); ++it) {
                int i4 = tid + it * NTF;
                float4 v = c1[i4];
                unsigned int g = V0 + 4u * (unsigned int)i4;
                INSERT(v.x, g); INSERT(v.y, g + 1); INSERT(v.z, g + 2); INSERT(v.w, g + 3);
            }
            if (tid < V2 / 4) {
                const float4* c2 = (const float4*)(cls2 + (size_t)b * V2);
                float4 v = c2[tid];
                unsigned int g = V0 + V1 + 4u * (unsigned int)tid;
                INSERT(v.x, g); INSERT(v.y, g + 1); INSERT(v.z, g + 2); INSERT(v.w, g + 3);
            }
#pragma unroll
            for (int j = 0; j < K; ++j) sKeys[tid * K + j] = keys[j];
        }
        for (int half = NTF / 2; half >= 1; half >>= 1) {
            __syncthreads();
            if (tid < half) {
                int aB = tid * K, bB = (tid + half) * K;
                unsigned long long ov[K];
                int ia = 0, ib = 0;
                unsigned long long av = sKeys[aB], bv = sKeys[bB];
#pragma unroll
                for (int p = 0; p < K; ++p) {
                    bool ta = (av >= bv);
                    ov[p] = ta ? av : bv;
                    if (ta) { ++ia; av = (ia < K) ? sKeys[aB + ia] : 0ull; }
                    else    { ++ib; bv = (ib < K) ? sKeys[bB + ib] : 0ull; }
                }
#pragma unroll
                for (int p = 0; p < K; ++p) sKeys[aB + p] = ov[p];
            }
        }
        __syncthreads();
        if (tid < K) sorted[tid] = sKeys[tid];
        __syncthreads();
    }

    // ---------------- Decode top-20 candidates ----------------
    if (tid < K) {
        unsigned long long key = sorted[tid];
        float score = __uint_as_float((unsigned int)(key >> 32));
        unsigned int g = ~((unsigned int)key);
        sScore[tid] = score;
        sValid[tid] = (score > 0.15f) ? 1 : 0;

        int v, D;
        const float* sp; const float* op;
        if (g < V0)           { v = (int)g;             D = 32; sp = shp0; op = off0; }
        else if (g < V0 + V1) { v = (int)(g - V0);      D = 16; sp = shp1; op = off1; }
        else                  { v = (int)(g - V0 - V1); D = 8;  sp = shp2; op = off2; }
        int Vl = D * D * D, HW = D * D;
        int z = v / HW, rem = v - z * HW, y = rem / D, x = rem - y * D;
        float stride = 128.0f / (float)D;
        const float* opb = op + (size_t)b * 3 * Vl;
        const float* spb = sp + (size_t)b * 3 * Vl;
        sBox[tid][0] = ((float)z + opb[v])          * stride;
        sBox[tid][1] = ((float)y + opb[Vl + v])     * stride;
        sBox[tid][2] = ((float)x + opb[2 * Vl + v]) * stride;
        sBox[tid][3] = spb[v];
        sBox[tid][4] = spb[Vl + v];
        sBox[tid][5] = spb[2 * Vl + v];
    }
    __syncthreads();

    // ---------------- Pairwise 3D IoU (20x20) ----------------
    // fp contract off: np reference computes c ± 0.5*s as mul-then-add, not FMA.
    for (int p = tid; p < K * K; p += NT) {
#pragma clang fp contract(off)
        int i = p / K, j = p % K;
        float ci0 = sBox[i][0], ci1 = sBox[i][1], ci2 = sBox[i][2];
        float si0 = fmaxf(sBox[i][3], 0.0f), si1 = fmaxf(sBox[i][4], 0.0f), si2 = fmaxf(sBox[i][5], 0.0f);
        float cj0 = sBox[j][0], cj1 = sBox[j][1], cj2 = sBox[j][2];
        float sj0 = fmaxf(sBox[j][3], 0.0f), sj1 = fmaxf(sBox[j][4], 0.0f), sj2 = fmaxf(sBox[j][5], 0.0f);
        float in0 = fmaxf(fminf(ci0 + 0.5f * si0, cj0 + 0.5f * sj0) - fmaxf(ci0 - 0.5f * si0, cj0 - 0.5f * sj0), 0.0f);
        float in1 = fmaxf(fminf(ci1 + 0.5f * si1, cj1 + 0.5f * sj1) - fmaxf(ci1 - 0.5f * si1, cj1 - 0.5f * sj1), 0.0f);
        float in2 = fmaxf(fminf(ci2 + 0.5f * si2, cj2 + 0.5f * sj2) - fmaxf(ci2 - 0.5f * si2, cj2 - 0.5f * sj2), 0.0f);
        float inter = in0 * in1 * in2;
        float voli = si0 * si1 * si2, volj = sj0 * sj1 * sj2;
        sIou[p] = inter / (voli + volj - inter + 1e-8f);
    }
    __syncthreads();

    // ---------------- Greedy NMS (sequential, thread 0) ----------------
    // keep state in a bitmask (not a runtime-indexed array) so it stays
    // in registers, never scratch.
    if (tid == 0) {
        unsigned int keepMask = 0u;
        int cnt = 0;
#pragma unroll
        for (int i = 0; i < K; ++i) sRow[i] = -1;
        for (int i = 0; i < K; ++i) {
            int sup = 0;
            for (int j = 0; j < i; ++j)
                sup |= ((keepMask >> j) & 1u) && (sIou[i * K + j] > 0.05f);
            int kp = sValid[i] && !sup;
            keepMask |= (unsigned int)kp << i;
            if (kp) { sRow[cnt] = i; ++cnt; }
        }
    }
    __syncthreads();

    // ---------------- Write output: [180][8] per image ----------------
    float* ob = out + (size_t)b * (M_OUT * 8);
    for (int e = tid; e < M_OUT * 8; e += NT) {
        int r = e >> 3, c = e & 7;
        float val = -1.0f;
        if (r < K) {
            int i = sRow[r];
            if (i >= 0) {
                if (c == 0)      val = 1.0f;
                else if (c == 1) val = sScore[i];
                else             val = sBox[i][c - 2];
            }
        }
        ob[e] = val;
    }
}

extern "C" void kernel_launch(void* const* d_in, const int* in_sizes, int n_in,
                              void* d_out, int out_size, void* d_ws, size_t ws_size,
                              hipStream_t stream) {
    const float* cls0 = (const float*)d_in[0];
    const float* shp0 = (const float*)d_in[1];
    const float* off0 = (const float*)d_in[2];
    const float* cls1 = (const float*)d_in[3];
    const float* shp1 = (const float*)d_in[4];
    const float* off1 = (const float*)d_in[5];
    const float* cls2 = (const float*)d_in[6];
    const float* shp2 = (const float*)d_in[7];
    const float* off2 = (const float*)d_in[8];
    float* out = (float*)d_out;

    // Single fused kernel: one block per image, no workspace traffic,
    // no inter-kernel boundary. (d_ws intentionally unused.)
    (void)d_ws; (void)ws_size;
    fused_kernel<<<BATCH, NT, 0, stream>>>(cls0, shp0, off0, cls1, shp1, off1,
                                           cls2, shp2, off2, out);
}